// Round 16
// baseline (187.549 us; speedup 1.0000x reference)
//
#include <hip/hip_runtime.h>

typedef __bf16 bf16;
typedef __bf16 bf16x4 __attribute__((ext_vector_type(4)));
typedef __bf16 bf16x8 __attribute__((ext_vector_type(8)));
typedef float f32x4 __attribute__((ext_vector_type(4)));

#define MFMA_16x16x32(a, b, c) __builtin_amdgcn_mfma_f32_16x16x32_bf16((a), (b), (c), 0, 0, 0)

#define B_ 8
#define N_ 1024
#define C_ 768
#define H_ 12
#define HD_ 64
#define KDIM 768

__device__ __forceinline__ void gload_lds16(const void* g, void* l) {
  __builtin_amdgcn_global_load_lds(
      (const __attribute__((address_space(1))) void*)g,
      (__attribute__((address_space(3))) void*)l, 16, 0, 0);
}

// ---------------------------------------------------------------------------
// mask dtype detection (robust to int8/int32/int64 storage)
// ---------------------------------------------------------------------------
__global__ __launch_bounds__(256) void detect_mask_kernel(const unsigned* __restrict__ m32,
                                                          int* __restrict__ flags) {
  const int i = blockIdx.x * 256 + threadIdx.x;
  if (i < 2048) {
    const unsigned v = m32[i];
    if (v > 1u) atomicOr(&flags[0], 1);
    if ((i & 1) && v != 0u) atomicOr(&flags[1], 1);
  }
}

// ---------------------------------------------------------------------------
// cvt: f32 -> bf16 for x, w_qkv, w_proj; bias[b*N+n] = mask ? -1e30 : log(size)
// ---------------------------------------------------------------------------
__global__ __launch_bounds__(256) void cvt_kernel(const float* __restrict__ x,
                                                  const float* __restrict__ wq,
                                                  const float* __restrict__ wp,
                                                  const float* __restrict__ size_in,
                                                  const void* __restrict__ mask_raw,
                                                  const int* __restrict__ flags,
                                                  bf16* __restrict__ xb,
                                                  bf16* __restrict__ wqb,
                                                  bf16* __restrict__ wpb,
                                                  float* __restrict__ biasb) {
  const int i = blockIdx.x * 256 + threadIdx.x;  // grid covers 6291456/4
  {
    const float4 v = ((const float4*)x)[i];
    bf16x4 o = {(bf16)v.x, (bf16)v.y, (bf16)v.z, (bf16)v.w};
    ((bf16x4*)xb)[i] = o;
  }
  if (i < 442368) {  // 2304*768/4
    const float4 v = ((const float4*)wq)[i];
    bf16x4 o = {(bf16)v.x, (bf16)v.y, (bf16)v.z, (bf16)v.w};
    ((bf16x4*)wqb)[i] = o;
  }
  if (i < 147456) {  // 768*768/4
    const float4 v = ((const float4*)wp)[i];
    bf16x4 o = {(bf16)v.x, (bf16)v.y, (bf16)v.z, (bf16)v.w};
    ((bf16x4*)wpb)[i] = o;
  }
  if (i < B_ * N_) {
    int mv;
    if (flags[0]) {
      mv = (int)((const unsigned char*)mask_raw)[i];
    } else if (flags[1]) {
      mv = ((const int*)mask_raw)[i];
    } else {  // int64
      const unsigned* m32 = (const unsigned*)mask_raw;
      mv = (int)(m32[2 * i] | m32[2 * i + 1]);
    }
    biasb[i] = mv ? -1e30f : logf(size_in[i]);
  }
}

// ---------------------------------------------------------------------------
// GEMM (NT): out[m][o] = sum_k A[m][k] * W[o][k].  M=8192, K=768.
// R16: 256x256 tile (FLOP/staged-byte 65 -> 131; staged L3 traffic halves),
// 8 waves (2M x 4N, wave-tile 128x64, acc[8][4]), BK=64, double-buffered LDS
// (128KB, 1 block/CU), one barrier per K-step, XOR bank swizzle both tiles
// (pre-swizzled global source + swizzled frag reads; R15-proven conflict-free).
// MODE 0: A linear [m][768]; scatter epilogue into q/k/vt (grid 32x9;
//         q/k/v boundaries at nt%3==0 -> no straddle).
// MODE 1: A in [b][h][n][64] layout; f32 epilogue outf = acc + bias (grid 32x3)
// ---------------------------------------------------------------------------
template <int MODE>
__global__ __launch_bounds__(512, 2) void gemm_bt(const bf16* __restrict__ A,
                                                  const bf16* __restrict__ W,
                                                  const float* __restrict__ bias,
                                                  bf16* __restrict__ out0,
                                                  bf16* __restrict__ out1,
                                                  bf16* __restrict__ out2,
                                                  float* __restrict__ outf) {
  __shared__ bf16 As[2][256 * 64];
  __shared__ bf16 Bs[2][256 * 64];
  const int bid = blockIdx.x;
  const int mt = bid % 32;
  const int nt = bid / 32;
  const int t = threadIdx.x;
  const int lane = t & 63, w = t >> 6;      // w 0..7
  const int wm = w >> 2, wn = w & 3;        // 2M x 4N
  const int l15 = lane & 15, lg = lane >> 4;

  f32x4 acc[8][4] = {};

  const int srow = t >> 3;                        // 0..63 (row within chunk)
  const int skel = ((t & 7) ^ (srow & 7)) * 8;    // pre-swizzled source slot
  const bf16* Ag = A + (size_t)(mt * 256) * KDIM;
  const bf16* Bg = W + (size_t)(nt * 256) * KDIM;
  const int bA = mt >> 2;              // MODE 1: batch of this M-tile
  const int nbase = (mt & 3) * 256;    // MODE 1: n-base of this M-tile

  // A/B global source for K-step st (element offset st*64), chunk c (64 rows)
#define ASRC(st, c)                                                          \
  ((MODE == 0)                                                               \
       ? (Ag + (size_t)((c) * 64 + srow) * KDIM + (st) * 64 + skel)          \
       : (A + (((size_t)(bA * 12 + (st)) * 1024) + nbase + (c) * 64 + srow)  \
              * 64 + skel))
#define BSRC(st, c) (Bg + (size_t)((c) * 64 + srow) * KDIM + (st) * 64 + skel)

  // prologue: stage K-step 0 into buffer 0 (8KB per chunk-round, 4 chunks)
#pragma unroll
  for (int c = 0; c < 4; ++c) {
    gload_lds16(ASRC(0, c), (char*)As[0] + c * 8192 + w * 1024);
    gload_lds16(BSRC(0, c), (char*)Bs[0] + c * 8192 + w * 1024);
  }
  __syncthreads();

  const int swz = l15 & 7;   // reader-side swizzle (row&7 == l15&7)

  for (int st = 0; st < KDIM / 64; ++st) {
    const int cur = st & 1;
    if (st < KDIM / 64 - 1) {  // stage next K-step into the other buffer
#pragma unroll
      for (int c = 0; c < 4; ++c) {
        gload_lds16(ASRC(st + 1, c), (char*)As[cur ^ 1] + c * 8192 + w * 1024);
        gload_lds16(BSRC(st + 1, c), (char*)Bs[cur ^ 1] + c * 8192 + w * 1024);
      }
    }
#pragma unroll
    for (int ks = 0; ks < 2; ++ks) {
      const int slot = ((ks * 4 + lg) ^ swz) * 8;
      bf16x8 af[8], bfr[4];
#pragma unroll
      for (int i = 0; i < 8; ++i)
        af[i] = *(const bf16x8*)(As[cur] + (wm * 128 + i * 16 + l15) * 64 + slot);
#pragma unroll
      for (int j = 0; j < 4; ++j)
        bfr[j] = *(const bf16x8*)(Bs[cur] + (wn * 64 + j * 16 + l15) * 64 + slot);
#pragma unroll
      for (int i = 0; i < 8; ++i)
#pragma unroll
        for (int j = 0; j < 4; ++j)
          acc[i][j] = MFMA_16x16x32(af[i], bfr[j], acc[i][j]);
    }
    __syncthreads();  // drains vmcnt (next-tile loads done); frees buf[cur]
  }
#undef ASRC
#undef BSRC

  if (MODE == 0) {
    const int which = nt / 3;  // 768 = 3*256, tiles never straddle
#pragma unroll
    for (int i = 0; i < 8; ++i)
#pragma unroll
      for (int j = 0; j < 4; ++j)
#pragma unroll
        for (int r = 0; r < 4; ++r) {
          const int m = mt * 256 + wm * 128 + i * 16 + lg * 4 + r;
          const int o = nt * 256 + wn * 64 + j * 16 + l15;
          const int b = m >> 10, n = m & 1023;
          const int f = o - which * 768;
          const int h = f >> 6, hd = f & 63;
          const bf16 bv = (bf16)acc[i][j][r];
          if (which == 0)
            out0[(((size_t)(b * 12 + h)) * 1024 + n) * 64 + hd] = bv;
          else if (which == 1)
            out1[(((size_t)(b * 12 + h)) * 1024 + n) * 64 + hd] = bv;
          else
            out2[(((size_t)(b * 12 + h)) * 64 + hd) * 1024 + n] = bv;
        }
  } else {
#pragma unroll
    for (int j = 0; j < 4; ++j) {
      const int o = nt * 256 + wn * 64 + j * 16 + l15;
      const float bv = bias[o];
#pragma unroll
      for (int i = 0; i < 8; ++i)
#pragma unroll
        for (int r = 0; r < 4; ++r) {
          const int m = mt * 256 + wm * 128 + i * 16 + lg * 4 + r;
          outf[(size_t)m * 768 + o] = acc[i][j][r] + bv;
        }
    }
  }
}

// ---------------------------------------------------------------------------
// k_mean (f32 out): kmean[b,n,hd] = mean_h k[b,h,n,hd]
// ---------------------------------------------------------------------------
__global__ __launch_bounds__(256) void kmean_kernel(const bf16* __restrict__ kbuf,
                                                    float* __restrict__ kmean) {
  const int i = blockIdx.x * 256 + threadIdx.x;
  if (i >= B_ * N_ * HD_) return;
  const int hd = i & 63;
  const int n = (i >> 6) & 1023;
  const int b = i >> 16;
  float s = 0.f;
#pragma unroll
  for (int h = 0; h < 12; ++h)
    s += (float)kbuf[(((size_t)(b * 12 + h)) * 1024 + n) * 64 + hd];
  kmean[i] = s * (1.0f / 12.0f);
}

// ---------------------------------------------------------------------------
// MFMA flash attention (R13-validated). Block = 8 waves (512 thr), each wave
// 2 q-tiles of 16 rows -> 256 q-rows/block; grid = 96 bh x 4 qt. Only FOUR
// blocks stream each bh's K/V -> HBM fetch floor ~111MB independent of the
// workgroup->XCD mapping. KBLK=64, double-buffered LDS K/V, swapped-operand
// QK^T, lane-local softmax, contiguous [b][h][n][64] store.
// ---------------------------------------------------------------------------
__global__ __launch_bounds__(512, 4) void attn_mfma(const bf16* __restrict__ qbuf,
                                                    const bf16* __restrict__ kbuf,
                                                    const bf16* __restrict__ vtbuf,
                                                    const float* __restrict__ biasb,
                                                    bf16* __restrict__ outws) {
  __shared__ bf16 Ks[2][4096];  // [64 rows][8 slots of 8 elems], swizzled
  __shared__ bf16 Vs[2][4096];
  const int id = blockIdx.x;
  const int qt = id & 3;
  const int bh = id >> 2;
  const int b = bh / 12;
  const int t = threadIdx.x, lane = t & 63, w = t >> 6;  // w 0..7
  const int l15 = lane & 15, lg = lane >> 4;
  const int qbase = qt * 256 + w * 16;   // tile0 rows; tile1 = qbase + 128

  const bf16* Q = qbuf + ((size_t)bh * 1024 + qbase) * 64;
  const bf16* Kp = kbuf + (size_t)bh * 65536;
  const bf16* Vt = vtbuf + (size_t)bh * 65536;
  const float* bias = biasb + b * 1024;

  // Q as B-operand: col=l15 (q-row), k-slots lg*8+e = d
  const bf16x8 qb0 = *(const bf16x8*)(Q + l15 * 64 + lg * 8);
  const bf16x8 qb1 = *(const bf16x8*)(Q + l15 * 64 + 32 + lg * 8);
  const bf16x8 qc0 = *(const bf16x8*)(Q + (128 + l15) * 64 + lg * 8);
  const bf16x8 qc1 = *(const bf16x8*)(Q + (128 + l15) * 64 + 32 + lg * 8);

  // staging: thread t fills LDS bytes [t*16, t*16+16) of each 8KB tile.
  // K row srow holds key pi(srow); phys slot (t&7) holds logical slot
  // (t&7)^(srow&7)  (bank swizzle via pre-swizzled source).
  const int srow = t >> 3;                 // 0..63
  const int dsl = (t & 7) ^ (srow & 7);
  const int kkey = 32 * ((srow >> 5) & 1) + 4 * ((srow >> 4) & 1) +
                   8 * ((srow >> 2) & 3) + (srow & 3);
  const bf16* srcK = Kp + kkey * 64 + dsl * 8;
  const bf16* srcV = Vt + (size_t)srow * 1024 + dsl * 8;

  gload_lds16(srcK, (char*)&Ks[0][0] + w * 1024);
  gload_lds16(srcV, (char*)&Vs[0][0] + w * 1024);
  __syncthreads();

  const int bb0 = 8 * lg;        // bias quad base (D-row=lg*4+j)
  const int swz = l15 & 7;

  f32x4 oacc[4] = {}, oacc2[4] = {};
  float m = -1e30f, l = 0.f;
  float m2 = -1e30f, l2 = 0.f;

  for (int kt = 0; kt < 16; ++kt) {
    const int cur = kt & 1;
    const int kb = kt * 64;
    if (kt < 15) {  // stage next tile into the other buffer
      gload_lds16(srcK + (size_t)(kb + 64) * 64, (char*)&Ks[cur ^ 1][0] + w * 1024);
      gload_lds16(srcV + (kb + 64), (char*)&Vs[cur ^ 1][0] + w * 1024);
    }

    const bf16* LK = Ks[cur];
    const bf16* LV = Vs[cur];
    float sv[4][4], sw[4][4];
#pragma unroll
    for (int f = 0; f < 4; ++f) {
      const int cf = 32 * (f >> 1) + 4 * (f & 1);
      const bf16* kj = LK + (f * 16 + l15) * 64;
      const bf16x8 ka0 = *(const bf16x8*)(kj + (lg ^ swz) * 8);
      const bf16x8 ka1 = *(const bf16x8*)(kj + ((lg + 4) ^ swz) * 8);
      f32x4 z = {}, y = {};
      z = MFMA_16x16x32(ka0, qb0, z);
      y = MFMA_16x16x32(ka0, qc0, y);
      z = MFMA_16x16x32(ka1, qb1, z);
      y = MFMA_16x16x32(ka1, qc1, y);
      const float4 bi = *(const float4*)(bias + kb + cf + bb0);
      sv[f][0] = z[0] * 0.125f + bi.x;
      sv[f][1] = z[1] * 0.125f + bi.y;
      sv[f][2] = z[2] * 0.125f + bi.z;
      sv[f][3] = z[3] * 0.125f + bi.w;
      sw[f][0] = y[0] * 0.125f + bi.x;
      sw[f][1] = y[1] * 0.125f + bi.y;
      sw[f][2] = y[2] * 0.125f + bi.z;
      sw[f][3] = y[3] * 0.125f + bi.w;
    }
    // per-tile max over 64 keys: 15 local + 2 shuffles each
    float mx = sv[0][0], mx2 = sw[0][0];
#pragma unroll
    for (int f = 0; f < 4; ++f)
#pragma unroll
      for (int j = 0; j < 4; ++j) {
        mx = fmaxf(mx, sv[f][j]);
        mx2 = fmaxf(mx2, sw[f][j]);
      }
    mx = fmaxf(mx, __shfl_xor(mx, 16, 64));
    mx = fmaxf(mx, __shfl_xor(mx, 32, 64));
    mx2 = fmaxf(mx2, __shfl_xor(mx2, 16, 64));
    mx2 = fmaxf(mx2, __shfl_xor(mx2, 32, 64));
    const float mn = fmaxf(m, mx);
    const float mn2 = fmaxf(m2, mx2);
    const float resc = __expf(m - mn);
    const float resc2 = __expf(m2 - mn2);
    m = mn;
    m2 = mn2;

    float rs = 0.f, rs2 = 0.f;
    bf16x8 pa0, pa1, pa2, pa3;
#pragma unroll
    for (int f = 0; f < 4; ++f)
#pragma unroll
      for (int j = 0; j < 4; ++j) {
        const float p = __expf(sv[f][j] - mn);
        const float p2 = __expf(sw[f][j] - mn2);
        rs += p;
        rs2 += p2;
        const bf16 pb = (bf16)p;
        const bf16 pb2 = (bf16)p2;
        if (f == 0) { pa0[j] = pb; pa2[j] = pb2; }
        else if (f == 1) { pa0[4 + j] = pb; pa2[4 + j] = pb2; }
        else if (f == 2) { pa1[j] = pb; pa3[j] = pb2; }
        else { pa1[4 + j] = pb; pa3[4 + j] = pb2; }
      }
    rs += __shfl_xor(rs, 16, 64);
    rs += __shfl_xor(rs, 32, 64);
    rs2 += __shfl_xor(rs2, 16, 64);
    rs2 += __shfl_xor(rs2, 32, 64);
    l = l * resc + rs;
    l2 = l2 * resc2 + rs2;

#pragma unroll
    for (int df = 0; df < 4; ++df) {
      const bf16* vj = LV + (df * 16 + l15) * 64;
      const bf16x8 va0 = *(const bf16x8*)(vj + (lg ^ swz) * 8);
      const bf16x8 va1 = *(const bf16x8*)(vj + ((lg + 4) ^ swz) * 8);
      f32x4 t4 = oacc[df];
      f32x4 u4 = oacc2[df];
#pragma unroll
      for (int j = 0; j < 4; ++j) {
        t4[j] *= resc;
        u4[j] *= resc2;
      }
      t4 = MFMA_16x16x32(va0, pa0, t4);
      u4 = MFMA_16x16x32(va0, pa2, u4);
      t4 = MFMA_16x16x32(va1, pa1, t4);
      u4 = MFMA_16x16x32(va1, pa3, u4);
      oacc[df] = t4;
      oacc2[df] = u4;
    }
    __syncthreads();  // drains vmcnt (stage t+1 done); frees buf[cur]
  }

  // contiguous store: attnw[b][h][n][64]; tile0 rows qbase.., tile1 +128
  const float inv = 1.0f / l;
  const float inv2 = 1.0f / l2;
  bf16* outp = outws + ((size_t)bh * 1024 + qbase + l15) * 64;
#pragma unroll
  for (int df = 0; df < 4; ++df) {
    bf16x4 ov = {(bf16)(oacc[df][0] * inv), (bf16)(oacc[df][1] * inv),
                 (bf16)(oacc[df][2] * inv), (bf16)(oacc[df][3] * inv)};
    *(bf16x4*)(outp + df * 16 + lg * 4) = ov;
    bf16x4 ov2 = {(bf16)(oacc2[df][0] * inv2), (bf16)(oacc2[df][1] * inv2),
                  (bf16)(oacc2[df][2] * inv2), (bf16)(oacc2[df][3] * inv2)};
    *(bf16x4*)(outp + (size_t)128 * 64 + df * 16 + lg * 4) = ov2;
  }
}

// ---------------------------------------------------------------------------
extern "C" void kernel_launch(void* const* d_in, const int* in_sizes, int n_in,
                              void* d_out, int out_size, void* d_ws, size_t ws_size,
                              hipStream_t stream) {
  const float* x       = (const float*)d_in[0];
  const float* size_in = (const float*)d_in[1];
  const void*  mask    = d_in[2];
  const float* w_qkv   = (const float*)d_in[3];
  const float* w_proj  = (const float*)d_in[4];
  const float* b_proj  = (const float*)d_in[5];
  float* out = (float*)d_out;   // f32 outputs per reference dtype

  if (n_in < 6 ||
      in_sizes[0] != 6291456 || in_sizes[1] != 8192 || in_sizes[2] != 8192 ||
      in_sizes[3] != 1769472 || in_sizes[4] != 589824 || in_sizes[5] != 768)
    return;

  const size_t QS = (size_t)B_ * H_ * N_ * HD_;  // 6291456 elems
  if (ws_size < 55083024) return;

  bf16* xb    = (bf16*)d_ws;       // dead after gemm<0>; reused as attnw
  bf16* qbuf  = xb + QS;
  bf16* kbuf  = qbuf + QS;
  bf16* vtbuf = kbuf + QS;
  bf16* wqb   = vtbuf + QS;        // 1769472 elems
  bf16* wpb   = wqb + 1769472;     // 589824 elems
  float* biasb = (float*)(wpb + 589824);
  int* flags = (int*)(biasb + 8192);
  bf16* attnw = xb;                // [b][h][n][64]

  hipMemsetAsync(flags, 0, 8, stream);
  detect_mask_kernel<<<8, 256, 0, stream>>>((const unsigned*)mask, flags);
  cvt_kernel<<<6144, 256, 0, stream>>>(x, w_qkv, w_proj, size_in, mask, flags,
                                       xb, wqb, wpb, biasb);
  gemm_bt<0><<<32 * 9, 512, 0, stream>>>(xb, wqb, nullptr, qbuf, kbuf, vtbuf, nullptr);
  kmean_kernel<<<2048, 256, 0, stream>>>(kbuf, out + (size_t)B_ * N_ * C_);
  attn_mfma<<<384, 512, 0, stream>>>(qbuf, kbuf, vtbuf, biasb, attnw);
  gemm_bt<1><<<32 * 3, 512, 0, stream>>>(attnw, wpb, b_proj, nullptr, nullptr, nullptr, out);
}